// Round 5
// baseline (271.429 us; speedup 1.0000x reference)
//
#include <hip/hip_runtime.h>

typedef unsigned short u16;
typedef unsigned int u32;
typedef __attribute__((ext_vector_type(4))) unsigned int u32x4;
typedef __attribute__((ext_vector_type(4))) float f32x4;
typedef __attribute__((ext_vector_type(8))) __bf16 bf16x8;

// Problem constants (fixed by the reference).
constexpr int NV    = 20000;
constexpr int ND    = 8;
constexpr int CH    = 16;
constexpr int NF    = 16;
constexpr int NVD   = NV * ND;        // 160000 y rows per batch
constexpr int K0    = 1024;           // conv contraction
constexpr int NCHUNK = 36;            // 1152 / 32 (chunks 32..35 = center term)
constexpr int MV    = 16;             // vertices per block -> 1250 blocks/launch
constexpr int ZSTR  = 40;             // padded z row stride (u16)

// ws layout (bytes): [0,10240000) y16 bf16 [B][NVD][CH]; [10240000,10534912) k2c
constexpr size_t K2C_OFF_B = 10240000;

__device__ __forceinline__ u16 f2bf(float x) {
    unsigned int u = __float_as_uint(x);
    unsigned int r = (u + 0x7fffu + ((u >> 16) & 1u)) >> 16;   // RNE
    return (u16)r;
}
__device__ __forceinline__ unsigned int pack2bf(float a, float b) {
    return (unsigned int)f2bf(a) | ((unsigned int)f2bf(b) << 16);
}

// ---------------- P: prep (y fp32 -> bf16 table) + k2c build, one launch ----------------
__global__ __launch_bounds__(256) void prep_k2(const float* __restrict__ y,
                                               const float* __restrict__ kern,
                                               const float* __restrict__ ck,
                                               u16* __restrict__ y16,
                                               u16* __restrict__ k2c) {
    int bx = blockIdx.x;
    if (bx < 1250) {
        int tid = bx * 256 + threadIdx.x;           // [0, 320000) = row of y / y16
        const float4* src = (const float4*)(y + (size_t)tid * 16);
        float4 v0 = src[0], v1 = src[1], v2 = src[2], v3 = src[3];
        u32x4 lo = {pack2bf(v0.x, v0.y), pack2bf(v0.z, v0.w), pack2bf(v1.x, v1.y), pack2bf(v1.z, v1.w)};
        u32x4 hi = {pack2bf(v2.x, v2.y), pack2bf(v2.z, v2.w), pack2bf(v3.x, v3.y), pack2bf(v3.z, v3.w)};
        u16* yd = y16 + (size_t)tid * 16;
        *(u32x4*)(yd)     = lo;
        *(u32x4*)(yd + 8) = hi;
    } else {
        int e = (bx - 1250) * 256 + threadIdx.x;    // [0, 36*4096)
        int i = e & 4095, kc = e >> 12;
        int n = i >> 5, kk = i & 31;
        int k = kc * 32 + kk;
        int w = n >> 4, f = n & 15;
        float val;
        if (k < K0) {
            int r = k >> 7, dd = (k >> 4) & 7, c = k & 15;
            int d = (dd - w) & 7;
            val = kern[((r * 8 + d) * 16 + c) * 16 + f];
        } else {
            int ke = k - K0;
            int d = ke >> 4, c = ke & 15;
            val = (d == w) ? ck[c * 16 + f] : 0.f;
        }
        k2c[e] = f2bf(val);
    }
}

// ---------------- fused gather + GEMM + epilogue (one batch per launch) ----------------
// Block: 16 vertices, 256 threads (4 waves), all 128 output cols.
// Gather decode: t = vl*16 + rdo*8 + q -> thread handles 4 B (2 ch) of z row (vl, rd=kc*2+rdo).
// Pipeline: gathers issued 2 chunks ahead (registers survive the barrier), combined+
// written to LDS 1 chunk ahead; B-fragments direct global->register (L2-resident k2c),
// prefetched 1 chunk ahead. One barrier per chunk. Epilogue: in-register max over the
// wave's 2 w's, cross-wave max via LDS atomicMax (relu => values >= 0).
struct Meta { int c0, c1, c2, a0, a1, a2; float w0, w1, w2; };

__global__ __launch_bounds__(256, 5) void geo_fused(const u16* __restrict__ y16b,
                                                    const u16* __restrict__ k2c,
                                                    const int* __restrict__ contrib,
                                                    const float* __restrict__ wbary,
                                                    const int* __restrict__ angles,
                                                    const float* __restrict__ bias,
                                                    float* __restrict__ outb) {
    __shared__ __align__(16) u16 Zb[2][MV * ZSTR];    // 2,560 B
    __shared__ int emax[MV * NF];                     // 1,024 B

    const int t = threadIdx.x;
    const int v0 = blockIdx.x * MV;
    // gather decode
    const int vl = t >> 4, rdo = (t >> 3) & 1, q = t & 7;   // q = dword within 32 B row
    // MFMA decode
    const int wc = t >> 6, lane = t & 63;
    const int lrow = lane & 15, lq = lane >> 4;

    const size_t mrow = (size_t)(v0 + vl) * 64;

#define LOAD_META(M, j)                                                            \
    {   size_t mb = (mrow + ((j) * 2 + rdo)) * 3;                                  \
        (M).c0 = __builtin_nontemporal_load(contrib + mb);                         \
        (M).c1 = __builtin_nontemporal_load(contrib + mb + 1);                     \
        (M).c2 = __builtin_nontemporal_load(contrib + mb + 2);                     \
        (M).a0 = __builtin_nontemporal_load(angles + mb);                          \
        (M).a1 = __builtin_nontemporal_load(angles + mb + 1);                      \
        (M).a2 = __builtin_nontemporal_load(angles + mb + 2);                      \
        (M).w0 = __builtin_nontemporal_load(wbary + mb);                           \
        (M).w1 = __builtin_nontemporal_load(wbary + mb + 1);                       \
        (M).w2 = __builtin_nontemporal_load(wbary + mb + 2); }

#define ISSUE_GATHER(M, g0, g1, g2, w0_, w1_, w2_)                                 \
    {   g0 = *(const u32*)(y16b + ((size_t)((M).c0 * 8 + (M).a0)) * 16 + q * 2);   \
        g1 = *(const u32*)(y16b + ((size_t)((M).c1 * 8 + (M).a1)) * 16 + q * 2);   \
        g2 = *(const u32*)(y16b + ((size_t)((M).c2 * 8 + (M).a2)) * 16 + q * 2);   \
        w0_ = (M).w0; w1_ = (M).w1; w2_ = (M).w2; }

#define CENTER_LOAD(kcn, g0)                                                       \
    {   g0 = *(const u32*)(y16b + ((size_t)((v0 + vl) * 8 + ((kcn) - 32) * 2 + rdo)) * 16 + q * 2); }

#define COMBINE_WRITE(g0, g1, g2, w0_, w1_, w2_, buf)                              \
    {   float x0 = 0.f, x1 = 0.f;                                                  \
        x0 += w0_ * __uint_as_float(g0 << 16);                                     \
        x1 += w0_ * __uint_as_float(g0 & 0xffff0000u);                             \
        x0 += w1_ * __uint_as_float(g1 << 16);                                     \
        x1 += w1_ * __uint_as_float(g1 & 0xffff0000u);                             \
        x0 += w2_ * __uint_as_float(g2 << 16);                                     \
        x1 += w2_ * __uint_as_float(g2 & 0xffff0000u);                             \
        *(u32*)(&Zb[buf][vl * ZSTR + rdo * 16 + q * 2]) = pack2bf(x0, x1); }

#define LOAD_B(kcn, d0, d1)                                                        \
    {   const u16* bp = k2c + (size_t)(kcn) * 4096 + (size_t)(wc * 32 + lrow) * 32 + lq * 8; \
        d0 = *(const bf16x8*)(bp);                                                 \
        d1 = *(const bf16x8*)(bp + 512); }

    // ---- prologue ----
    Meta M;
    u32 ga0, ga1, ga2, gb0, gb1, gb2;
    float wa0, wa1, wa2, wb0, wb1, wb2;
    bf16x8 Bv0, Bv1, Bn0, Bn1;

    LOAD_META(M, 0);
    ISSUE_GATHER(M, ga0, ga1, ga2, wa0, wa1, wa2);    // chunk 0
    LOAD_META(M, 1);
    LOAD_B(0, Bv0, Bv1);
    COMBINE_WRITE(ga0, ga1, ga2, wa0, wa1, wa2, 0);   // chunk 0 -> Zb[0]
    ISSUE_GATHER(M, ga0, ga1, ga2, wa0, wa1, wa2);    // chunk 1 in flight
    LOAD_META(M, 2);
    __syncthreads();

    f32x4 acc0 = (f32x4){0.f, 0.f, 0.f, 0.f};
    f32x4 acc1 = (f32x4){0.f, 0.f, 0.f, 0.f};

    // invariant at top of iter kc: Zb[kc&1] published; (ga,wa) = in-flight chunk kc+1;
    // (Bv0,Bv1) = B-frags of chunk kc; M = meta(kc+2) when kc+2 < 32.
    for (int kc = 0; kc < NCHUNK; ++kc) {
        const int p = kc & 1;
        const int c1 = kc + 1, c2 = kc + 2;
        if (c2 < NCHUNK) {
            if (c2 < 32) { ISSUE_GATHER(M, gb0, gb1, gb2, wb0, wb1, wb2); }
            else         { CENTER_LOAD(c2, gb0); }
        }
        if (kc + 3 < 32) LOAD_META(M, kc + 3);
        if (c1 < NCHUNK) LOAD_B(c1, Bn0, Bn1);

        bf16x8 af = *(const bf16x8*)(&Zb[p][lrow * ZSTR + lq * 8]);
        acc0 = __builtin_amdgcn_mfma_f32_16x16x32_bf16(af, Bv0, acc0, 0, 0, 0);
        acc1 = __builtin_amdgcn_mfma_f32_16x16x32_bf16(af, Bv1, acc1, 0, 0, 0);

        if (c1 < NCHUNK) {
            const int wbuf = c1 & 1;
            if (c1 < 32) { COMBINE_WRITE(ga0, ga1, ga2, wa0, wa1, wa2, wbuf); }
            else         { *(u32*)(&Zb[wbuf][vl * ZSTR + rdo * 16 + q * 2]) = ga0; }
            ga0 = gb0; ga1 = gb1; ga2 = gb2;
            wa0 = wb0; wa1 = wb1; wa2 = wb2;
            Bv0 = Bn0; Bv1 = Bn1;
        }
        __syncthreads();
    }

    // ---- epilogue: +bias, relu, max over w; lane's 2 accs are w = wc*2 + {0,1}, f = lrow
    emax[t] = 0;
    __syncthreads();
    const float bb = bias[lrow];
    #pragma unroll
    for (int reg = 0; reg < 4; ++reg) {
        float m = fmaxf(0.f, acc0[reg] + bb);
        m = fmaxf(m, acc1[reg] + bb);
        atomicMax(&emax[(lq * 4 + reg) * NF + lrow], __float_as_int(m));
    }
    __syncthreads();
    {
        int row = t >> 4, f = t & 15;
        __builtin_nontemporal_store(__int_as_float(emax[t]), outb + (size_t)(v0 + row) * NF + f);
    }
#undef LOAD_META
#undef ISSUE_GATHER
#undef CENTER_LOAD
#undef COMBINE_WRITE
#undef LOAD_B
}

extern "C" void kernel_launch(void* const* d_in, const int* in_sizes, int n_in,
                              void* d_out, int out_size, void* d_ws, size_t ws_size,
                              hipStream_t stream) {
    const float* y      = (const float*)d_in[0];
    const int*   contrib= (const int*)d_in[1];
    const float* wbary  = (const float*)d_in[2];
    const int*   angles = (const int*)d_in[3];
    const float* kern   = (const float*)d_in[4];
    const float* ck     = (const float*)d_in[5];
    const float* bias   = (const float*)d_in[6];
    float* out = (float*)d_out;

    u16* y16 = (u16*)d_ws;
    u16* k2c = (u16*)((char*)d_ws + K2C_OFF_B);   // needs ws_size >= 10,534,912 B

    prep_k2<<<1250 + 576, 256, 0, stream>>>(y, kern, ck, y16, k2c);
    // batch-separate launches: keeps the random working set at one 5.12 MB table half
    geo_fused<<<NV / MV, 256, 0, stream>>>(y16, k2c, contrib, wbary, angles, bias, out);
    geo_fused<<<NV / MV, 256, 0, stream>>>(y16 + (size_t)NVD * CH, k2c, contrib, wbary, angles,
                                           bias, out + (size_t)NV * NF);
}

// Round 6
// 239.370 us; speedup vs baseline: 1.1339x; 1.1339x over previous
//
#include <hip/hip_runtime.h>

typedef unsigned short u16;
typedef unsigned int u32;
typedef __attribute__((ext_vector_type(4))) unsigned int u32x4;
typedef __attribute__((ext_vector_type(4))) float f32x4;
typedef __attribute__((ext_vector_type(8))) __bf16 bf16x8;

// Problem constants (fixed by the reference).
constexpr int NV    = 20000;
constexpr int ND    = 8;
constexpr int CH    = 16;
constexpr int NF    = 16;
constexpr int NVD   = NV * ND;        // 160000 y rows per batch
constexpr int K0    = 1024;           // conv contraction
constexpr int NCHUNK = 36;            // 1152 / 32 (chunks 32..35 = center term)
constexpr int MV    = 16;             // vertices per block -> 1250 blocks/launch
constexpr int ZSTR  = 1160;           // padded z row stride (u16): 1152+8

// ws layout (bytes): [0,10240000) y16 bf16 [B][NVD][CH]; [10240000,10534912) k2c
constexpr size_t K2C_OFF_B = 10240000;

__device__ __forceinline__ u16 f2bf(float x) {
    unsigned int u = __float_as_uint(x);
    unsigned int r = (u + 0x7fffu + ((u >> 16) & 1u)) >> 16;   // RNE
    return (u16)r;
}
__device__ __forceinline__ unsigned int pack2bf(float a, float b) {
    return (unsigned int)f2bf(a) | ((unsigned int)f2bf(b) << 16);
}

// ---------------- P: prep (y fp32 -> bf16 table) + k2c build, one launch ----------------
__global__ __launch_bounds__(256) void prep_k2(const float* __restrict__ y,
                                               const float* __restrict__ kern,
                                               const float* __restrict__ ck,
                                               u16* __restrict__ y16,
                                               u16* __restrict__ k2c) {
    int bx = blockIdx.x;
    if (bx < 1250) {
        int tid = bx * 256 + threadIdx.x;           // [0, 320000) = row of y / y16
        const float4* src = (const float4*)(y + (size_t)tid * 16);
        float4 v0 = src[0], v1 = src[1], v2 = src[2], v3 = src[3];
        u32x4 lo = {pack2bf(v0.x, v0.y), pack2bf(v0.z, v0.w), pack2bf(v1.x, v1.y), pack2bf(v1.z, v1.w)};
        u32x4 hi = {pack2bf(v2.x, v2.y), pack2bf(v2.z, v2.w), pack2bf(v3.x, v3.y), pack2bf(v3.z, v3.w)};
        u16* yd = y16 + (size_t)tid * 16;
        *(u32x4*)(yd)     = lo;
        *(u32x4*)(yd + 8) = hi;
    } else {
        int e = (bx - 1250) * 256 + threadIdx.x;    // [0, 36*4096)
        int i = e & 4095, kc = e >> 12;
        int n = i >> 5, kk = i & 31;
        int k = kc * 32 + kk;
        int w = n >> 4, f = n & 15;
        float val;
        if (k < K0) {
            int r = k >> 7, dd = (k >> 4) & 7, c = k & 15;
            int d = (dd - w) & 7;
            val = kern[((r * 8 + d) * 16 + c) * 16 + f];
        } else {
            int ke = k - K0;
            int d = ke >> 4, c = ke & 15;
            val = (d == w) ? ck[c * 16 + f] : 0.f;
        }
        k2c[e] = f2bf(val);
    }
}

// ---------------- fused: bulk gather -> LDS, ONE barrier, GEMM + epilogue --------------
// Block: 16 vertices, 256 threads (4 waves). Phase 1: all 1024 (vl,rd) z-rows gathered
// with fully independent loads (4 items/thread, 12 random 16B-pair loads in flight, no
// intervening barriers) + coalesced center rows. Phase 2: 36-chunk MFMA loop, A from
// LDS, B direct global->register (k2c is L2-hot, 288 KB). Epilogue: in-register max
// over the wave's 2 w's, cross-wave max via LDS atomicMax (relu => values >= 0).
__global__ __launch_bounds__(256, 4) void geo_fused(const u16* __restrict__ y16b,
                                                    const u16* __restrict__ k2c,
                                                    const int* __restrict__ contrib,
                                                    const float* __restrict__ wbary,
                                                    const int* __restrict__ angles,
                                                    const float* __restrict__ bias,
                                                    float* __restrict__ outb) {
    __shared__ __align__(16) u16 Z[MV * ZSTR];        // 37,120 B
    __shared__ int emax[MV * NF];                     //  1,024 B

    const int t = threadIdx.x;
    const int v0 = blockIdx.x * MV;

    // ---- phase 1a: center rows (coalesced): Z[vl][1024 + i*8 ..] = y16b row block ----
    {
        int vl = t >> 4, i = t & 15;                  // 16 B unit of the 256 B center span
        u32x4 val = *(const u32x4*)(y16b + (size_t)(v0 + vl) * 128 + i * 8);
        *(u32x4*)(&Z[vl * ZSTR + K0 + i * 8]) = val;
    }

    // ---- phase 1b: bulk gather, 4 items per thread, vl = t&15 (rd-major items) ----
    #pragma unroll 2
    for (int it = 0; it < 4; ++it) {
        int item = it * 256 + t;
        int vl = item & 15, rd = item >> 4;
        size_t mb = ((size_t)(v0 + vl) * 64 + rd) * 3;
        int   c0 = __builtin_nontemporal_load(contrib + mb);
        int   c1 = __builtin_nontemporal_load(contrib + mb + 1);
        int   c2 = __builtin_nontemporal_load(contrib + mb + 2);
        int   a0 = __builtin_nontemporal_load(angles + mb);
        int   a1 = __builtin_nontemporal_load(angles + mb + 1);
        int   a2 = __builtin_nontemporal_load(angles + mb + 2);
        float w0 = __builtin_nontemporal_load(wbary + mb);
        float w1 = __builtin_nontemporal_load(wbary + mb + 1);
        float w2 = __builtin_nontemporal_load(wbary + mb + 2);
        const u16* s0 = y16b + (size_t)(c0 * 8 + a0) * 16;
        const u16* s1 = y16b + (size_t)(c1 * 8 + a1) * 16;
        const u16* s2 = y16b + (size_t)(c2 * 8 + a2) * 16;
        u32x4 p00 = *(const u32x4*)(s0), p01 = *(const u32x4*)(s0 + 8);
        u32x4 p10 = *(const u32x4*)(s1), p11 = *(const u32x4*)(s1 + 8);
        u32x4 p20 = *(const u32x4*)(s2), p21 = *(const u32x4*)(s2 + 8);
        float acc[CH];
        #pragma unroll
        for (int q = 0; q < 4; ++q) {
            acc[2*q]   = w0 * __uint_as_float(p00[q] << 16)
                       + w1 * __uint_as_float(p10[q] << 16)
                       + w2 * __uint_as_float(p20[q] << 16);
            acc[2*q+1] = w0 * __uint_as_float(p00[q] & 0xffff0000u)
                       + w1 * __uint_as_float(p10[q] & 0xffff0000u)
                       + w2 * __uint_as_float(p20[q] & 0xffff0000u);
            acc[8+2*q]   = w0 * __uint_as_float(p01[q] << 16)
                         + w1 * __uint_as_float(p11[q] << 16)
                         + w2 * __uint_as_float(p21[q] << 16);
            acc[8+2*q+1] = w0 * __uint_as_float(p01[q] & 0xffff0000u)
                         + w1 * __uint_as_float(p11[q] & 0xffff0000u)
                         + w2 * __uint_as_float(p21[q] & 0xffff0000u);
        }
        u32x4 o0, o1;
        #pragma unroll
        for (int q = 0; q < 4; ++q) {
            o0[q] = pack2bf(acc[2*q], acc[2*q+1]);
            o1[q] = pack2bf(acc[8+2*q], acc[8+2*q+1]);
        }
        u16* dst = &Z[vl * ZSTR + rd * 16];
        *(u32x4*)(dst)     = o0;
        *(u32x4*)(dst + 8) = o1;
    }
    __syncthreads();

    // ---- phase 2: GEMM. wave wc covers cols wc*32..+31 (2 tiles), rows = 16 vertices.
    const int wc = t >> 6, lane = t & 63;
    const int lrow = lane & 15, lq = lane >> 4;
    const u16* bbase = k2c + (size_t)(wc * 32 + lrow) * 32 + lq * 8;

    f32x4 acc0 = (f32x4){0.f, 0.f, 0.f, 0.f};
    f32x4 acc1 = (f32x4){0.f, 0.f, 0.f, 0.f};
    bf16x8 Bv0 = *(const bf16x8*)(bbase);
    bf16x8 Bv1 = *(const bf16x8*)(bbase + 512);

    for (int kc = 0; kc < NCHUNK; ++kc) {
        bf16x8 Bn0, Bn1;
        if (kc + 1 < NCHUNK) {
            const u16* bp = bbase + (size_t)(kc + 1) * 4096;
            Bn0 = *(const bf16x8*)(bp);
            Bn1 = *(const bf16x8*)(bp + 512);
        }
        bf16x8 af = *(const bf16x8*)(&Z[lrow * ZSTR + kc * 32 + lq * 8]);
        acc0 = __builtin_amdgcn_mfma_f32_16x16x32_bf16(af, Bv0, acc0, 0, 0, 0);
        acc1 = __builtin_amdgcn_mfma_f32_16x16x32_bf16(af, Bv1, acc1, 0, 0, 0);
        Bv0 = Bn0; Bv1 = Bn1;
    }

    // ---- epilogue: +bias, relu, max over w; lane's accs: w = 2*wc + {0,1}, f = lrow
    emax[t] = 0;
    __syncthreads();
    const float bb = bias[lrow];
    #pragma unroll
    for (int reg = 0; reg < 4; ++reg) {
        float m = fmaxf(0.f, acc0[reg] + bb);
        m = fmaxf(m, acc1[reg] + bb);
        atomicMax(&emax[(lq * 4 + reg) * NF + lrow], __float_as_int(m));
    }
    __syncthreads();
    {
        int row = t >> 4, f = t & 15;
        __builtin_nontemporal_store(__int_as_float(emax[t]),
                                    outb + (size_t)(v0 + row) * NF + f);
    }
}

extern "C" void kernel_launch(void* const* d_in, const int* in_sizes, int n_in,
                              void* d_out, int out_size, void* d_ws, size_t ws_size,
                              hipStream_t stream) {
    const float* y      = (const float*)d_in[0];
    const int*   contrib= (const int*)d_in[1];
    const float* wbary  = (const float*)d_in[2];
    const int*   angles = (const int*)d_in[3];
    const float* kern   = (const float*)d_in[4];
    const float* ck     = (const float*)d_in[5];
    const float* bias   = (const float*)d_in[6];
    float* out = (float*)d_out;

    u16* y16 = (u16*)d_ws;
    u16* k2c = (u16*)((char*)d_ws + K2C_OFF_B);   // needs ws_size >= 10,534,912 B

    prep_k2<<<1250 + 576, 256, 0, stream>>>(y, kern, ck, y16, k2c);
    // batch-separate launches: live random set = one 5.12 MB table half
    geo_fused<<<NV / MV, 256, 0, stream>>>(y16, k2c, contrib, wbary, angles, bias, out);
    geo_fused<<<NV / MV, 256, 0, stream>>>(y16 + (size_t)NVD * CH, k2c, contrib, wbary, angles,
                                           bias, out + (size_t)NV * NF);
}

// Round 7
// 234.305 us; speedup vs baseline: 1.1584x; 1.0216x over previous
//
#include <hip/hip_runtime.h>

typedef unsigned short u16;
typedef unsigned int u32;
typedef __attribute__((ext_vector_type(4))) unsigned int u32x4;
typedef __attribute__((ext_vector_type(4))) float f32x4;
typedef __attribute__((ext_vector_type(8))) __bf16 bf16x8;

// Problem constants (fixed by the reference).
constexpr int NV    = 20000;
constexpr int ND    = 8;
constexpr int CH    = 16;
constexpr int NF    = 16;
constexpr int NVD   = NV * ND;        // 160000 y rows per batch
constexpr int K0    = 1024;           // conv contraction
constexpr int NCHUNK = 36;            // 1152 / 32 (chunks 32..35 = center term)
constexpr int MV    = 16;             // vertices per block -> 1250 blocks/launch
constexpr int ZSTR  = 1160;           // padded z row stride (u16): 1152+8 (2-way LDS, free)

// ws layout (bytes): [0,10240000) y16 bf16 [B][NVD][CH]; [10240000,10534912) k2c
constexpr size_t K2C_OFF_B = 10240000;

__device__ __forceinline__ u16 f2bf(float x) {
    unsigned int u = __float_as_uint(x);
    unsigned int r = (u + 0x7fffu + ((u >> 16) & 1u)) >> 16;   // RNE
    return (u16)r;
}
__device__ __forceinline__ unsigned int pack2bf(float a, float b) {
    return (unsigned int)f2bf(a) | ((unsigned int)f2bf(b) << 16);
}

// ---------------- P: prep (y fp32 -> bf16 table) + k2c build, one launch ----------------
__global__ __launch_bounds__(256) void prep_k2(const float* __restrict__ y,
                                               const float* __restrict__ kern,
                                               const float* __restrict__ ck,
                                               u16* __restrict__ y16,
                                               u16* __restrict__ k2c) {
    int bx = blockIdx.x;
    if (bx < 1250) {
        int tid = bx * 256 + threadIdx.x;           // [0, 320000) = row of y / y16
        const float4* src = (const float4*)(y + (size_t)tid * 16);
        float4 v0 = src[0], v1 = src[1], v2 = src[2], v3 = src[3];
        u32x4 lo = {pack2bf(v0.x, v0.y), pack2bf(v0.z, v0.w), pack2bf(v1.x, v1.y), pack2bf(v1.z, v1.w)};
        u32x4 hi = {pack2bf(v2.x, v2.y), pack2bf(v2.z, v2.w), pack2bf(v3.x, v3.y), pack2bf(v3.z, v3.w)};
        u16* yd = y16 + (size_t)tid * 16;
        *(u32x4*)(yd)     = lo;
        *(u32x4*)(yd + 8) = hi;
    } else {
        int e = (bx - 1250) * 256 + threadIdx.x;    // [0, 36*4096)
        int i = e & 4095, kc = e >> 12;
        int n = i >> 5, kk = i & 31;
        int k = kc * 32 + kk;
        int w = n >> 4, f = n & 15;
        float val;
        if (k < K0) {
            int r = k >> 7, dd = (k >> 4) & 7, c = k & 15;
            int d = (dd - w) & 7;
            val = kern[((r * 8 + d) * 16 + c) * 16 + f];
        } else {
            int ke = k - K0;
            int d = ke >> 4, c = ke & 15;
            val = (d == w) ? ck[c * 16 + f] : 0.f;
        }
        k2c[e] = f2bf(val);
    }
}

// ---------------- fused: bulk gather -> LDS, ONE barrier, GEMM + epilogue --------------
// Block: 16 vertices, 512 threads (8 waves -> 32 waves/CU at 4 blocks/CU).
// Phase 1: all 1024 (vl,rd) z-rows gathered with fully independent loads (2 items/thread,
// 6 random 16B loads in flight each, no intervening barriers) + coalesced center rows.
// Phase 2: 36-chunk MFMA loop, A from LDS, B direct global->register (k2c L2-hot,
// 288 KB), 2-deep prefetch. Epilogue: wave wc owns w=wc; cross-wave max via LDS
// atomicMax (relu => values >= 0).
__global__ __launch_bounds__(512, 8) void geo_fused(const u16* __restrict__ y16b,
                                                    const u16* __restrict__ k2c,
                                                    const int* __restrict__ contrib,
                                                    const float* __restrict__ wbary,
                                                    const int* __restrict__ angles,
                                                    const float* __restrict__ bias,
                                                    float* __restrict__ outb) {
    __shared__ __align__(16) u16 Z[MV * ZSTR];        // 37,120 B
    __shared__ int emax[MV * NF];                     //  1,024 B

    const int t = threadIdx.x;
    const int v0 = blockIdx.x * MV;

    // ---- phase 1a: center rows (coalesced, 8 B/thread): Z[vl][1024 + i*4 ..] ----
    {
        int vl = t >> 5, i = t & 31;                  // i = 8 B unit of the 256 B center span
        uint2 val = *(const uint2*)(y16b + (size_t)(v0 + vl) * 128 + i * 4);
        *(uint2*)(&Z[vl * ZSTR + K0 + i * 4]) = val;
    }

    // ---- phase 1b: bulk gather, 2 items per thread, vl = t&15 (rd-major items) ----
    #pragma unroll
    for (int it = 0; it < 2; ++it) {
        int item = it * 512 + t;
        int vl = item & 15, rd = item >> 4;
        size_t mb = ((size_t)(v0 + vl) * 64 + rd) * 3;
        int   c0 = __builtin_nontemporal_load(contrib + mb);
        int   c1 = __builtin_nontemporal_load(contrib + mb + 1);
        int   c2 = __builtin_nontemporal_load(contrib + mb + 2);
        int   a0 = __builtin_nontemporal_load(angles + mb);
        int   a1 = __builtin_nontemporal_load(angles + mb + 1);
        int   a2 = __builtin_nontemporal_load(angles + mb + 2);
        float w0 = __builtin_nontemporal_load(wbary + mb);
        float w1 = __builtin_nontemporal_load(wbary + mb + 1);
        float w2 = __builtin_nontemporal_load(wbary + mb + 2);
        const u16* s0 = y16b + (size_t)(c0 * 8 + a0) * 16;
        const u16* s1 = y16b + (size_t)(c1 * 8 + a1) * 16;
        const u16* s2 = y16b + (size_t)(c2 * 8 + a2) * 16;
        u32x4 p00 = *(const u32x4*)(s0), p01 = *(const u32x4*)(s0 + 8);
        u32x4 p10 = *(const u32x4*)(s1), p11 = *(const u32x4*)(s1 + 8);
        u32x4 p20 = *(const u32x4*)(s2), p21 = *(const u32x4*)(s2 + 8);
        float acc[CH];
        #pragma unroll
        for (int q = 0; q < 4; ++q) {
            acc[2*q]   = w0 * __uint_as_float(p00[q] << 16)
                       + w1 * __uint_as_float(p10[q] << 16)
                       + w2 * __uint_as_float(p20[q] << 16);
            acc[2*q+1] = w0 * __uint_as_float(p00[q] & 0xffff0000u)
                       + w1 * __uint_as_float(p10[q] & 0xffff0000u)
                       + w2 * __uint_as_float(p20[q] & 0xffff0000u);
            acc[8+2*q]   = w0 * __uint_as_float(p01[q] << 16)
                         + w1 * __uint_as_float(p11[q] << 16)
                         + w2 * __uint_as_float(p21[q] << 16);
            acc[8+2*q+1] = w0 * __uint_as_float(p01[q] & 0xffff0000u)
                         + w1 * __uint_as_float(p11[q] & 0xffff0000u)
                         + w2 * __uint_as_float(p21[q] & 0xffff0000u);
        }
        u32x4 o0, o1;
        #pragma unroll
        for (int q = 0; q < 4; ++q) {
            o0[q] = pack2bf(acc[2*q], acc[2*q+1]);
            o1[q] = pack2bf(acc[8+2*q], acc[8+2*q+1]);
        }
        u16* dst = &Z[vl * ZSTR + rd * 16];
        *(u32x4*)(dst)     = o0;
        *(u32x4*)(dst + 8) = o1;
    }
    __syncthreads();

    // ---- phase 2: GEMM. wave wc covers cols wc*16..+15 (w = wc), rows = 16 vertices.
    const int wc = t >> 6, lane = t & 63;
    const int lrow = lane & 15, lq = lane >> 4;
    const u16* bbase = k2c + (size_t)(wc * 16 + lrow) * 32 + lq * 8;

    f32x4 acc0 = (f32x4){0.f, 0.f, 0.f, 0.f};
    bf16x8 Bv = *(const bf16x8*)(bbase);
    bf16x8 Bn = *(const bf16x8*)(bbase + 4096);

    for (int kc = 0; kc < NCHUNK; ++kc) {
        bf16x8 Bnn;
        if (kc + 2 < NCHUNK)
            Bnn = *(const bf16x8*)(bbase + (size_t)(kc + 2) * 4096);
        bf16x8 af = *(const bf16x8*)(&Z[lrow * ZSTR + kc * 32 + lq * 8]);
        acc0 = __builtin_amdgcn_mfma_f32_16x16x32_bf16(af, Bv, acc0, 0, 0, 0);
        Bv = Bn; Bn = Bnn;
    }

    // ---- epilogue: +bias, relu, max over w; wave wc's acc: w = wc, f = lrow ----
    if (t < MV * NF) emax[t] = 0;
    __syncthreads();
    const float bb = bias[lrow];
    #pragma unroll
    for (int reg = 0; reg < 4; ++reg) {
        float m = fmaxf(0.f, acc0[reg] + bb);
        atomicMax(&emax[(lq * 4 + reg) * NF + lrow], __float_as_int(m));
    }
    __syncthreads();
    if (t < MV * NF) {
        int row = t >> 4, f = t & 15;
        __builtin_nontemporal_store(__int_as_float(emax[t]),
                                    outb + (size_t)(v0 + row) * NF + f);
    }
}

extern "C" void kernel_launch(void* const* d_in, const int* in_sizes, int n_in,
                              void* d_out, int out_size, void* d_ws, size_t ws_size,
                              hipStream_t stream) {
    const float* y      = (const float*)d_in[0];
    const int*   contrib= (const int*)d_in[1];
    const float* wbary  = (const float*)d_in[2];
    const int*   angles = (const int*)d_in[3];
    const float* kern   = (const float*)d_in[4];
    const float* ck     = (const float*)d_in[5];
    const float* bias   = (const float*)d_in[6];
    float* out = (float*)d_out;

    u16* y16 = (u16*)d_ws;
    u16* k2c = (u16*)((char*)d_ws + K2C_OFF_B);   // needs ws_size >= 10,534,912 B

    prep_k2<<<1250 + 576, 256, 0, stream>>>(y, kern, ck, y16, k2c);
    // batch-separate launches: live random set = one 5.12 MB table half (R3/R6 lesson:
    // merging batches doubles the live set -> miss blow-up; isolation is worth the
    // 46 MB meta re-read)
    geo_fused<<<NV / MV, 512, 0, stream>>>(y16, k2c, contrib, wbary, angles, bias, out);
    geo_fused<<<NV / MV, 512, 0, stream>>>(y16 + (size_t)NVD * CH, k2c, contrib, wbary, angles,
                                           bias, out + (size_t)NV * NF);
}